// Round 4
// baseline (481.001 us; speedup 1.0000x reference)
//
#include <hip/hip_runtime.h>

typedef __bf16 bf16x8 __attribute__((ext_vector_type(8)));
typedef float f32x4 __attribute__((ext_vector_type(4)));
typedef unsigned short u16;

#define EMB 1024
#define SEQ 2048
#define BATCH 2
#define HEADS 16
#define HEAD_DIM 64
#define FF 4096
#define ROWS (BATCH * SEQ)  // 4096

static __device__ __forceinline__ u16 f2bf(float f) {
    unsigned int u = __builtin_bit_cast(unsigned int, f);
    unsigned int r = (u + 0x7FFFu + ((u >> 16) & 1u)) >> 16;
    return (u16)r;
}

// async global->LDS, 16B per lane. LDS dest must be wave-uniform base (HW adds lane*16).
static __device__ __forceinline__ void gload16(const u16* g, u16* l) {
    __builtin_amdgcn_global_load_lds(
        (const __attribute__((address_space(1))) unsigned int*)(const void*)g,
        (__attribute__((address_space(3))) unsigned int*)(void*)l, 16, 0, 0);
}

// ---------------- transpose + convert: f32 [R][C] -> bf16 [C][R] ----------------
__global__ __launch_bounds__(256) void transpose_f32_to_bf16(
    const float* __restrict__ in, u16* __restrict__ out, int R, int C) {
    __shared__ float tile[32][33];
    int c0 = blockIdx.x * 32, r0 = blockIdx.y * 32;
    int tx = threadIdx.x & 31, ty = threadIdx.x >> 5;  // ty: 0..7
#pragma unroll
    for (int i = 0; i < 32; i += 8)
        tile[ty + i][tx] = in[(size_t)(r0 + ty + i) * C + c0 + tx];
    __syncthreads();
#pragma unroll
    for (int i = 0; i < 32; i += 8)
        out[(size_t)(c0 + ty + i) * R + r0 + tx] = f2bf(tile[tx][ty + i]);
}

// ---------------- LayerNorm: f32 [rows][1024] -> bf16 ----------------
__global__ __launch_bounds__(256) void ln_kernel(
    const float* __restrict__ x, const float* __restrict__ gamma,
    const float* __restrict__ beta, u16* __restrict__ out) {
    int row = blockIdx.x;
    int t = threadIdx.x;
    float4 v = reinterpret_cast<const float4*>(x + (size_t)row * EMB)[t];
    float s = v.x + v.y + v.z + v.w;
    float s2 = v.x * v.x + v.y * v.y + v.z * v.z + v.w * v.w;
#pragma unroll
    for (int off = 1; off < 64; off <<= 1) {
        s += __shfl_xor(s, off);
        s2 += __shfl_xor(s2, off);
    }
    __shared__ float sm[8];
    int wid = t >> 6;
    if ((t & 63) == 0) { sm[wid] = s; sm[wid + 4] = s2; }
    __syncthreads();
    s = sm[0] + sm[1] + sm[2] + sm[3];
    s2 = sm[4] + sm[5] + sm[6] + sm[7];
    float mean = s * (1.0f / EMB);
    float var = s2 * (1.0f / EMB) - mean * mean;
    float inv = rsqrtf(var + 1e-5f);
    float4 gv = reinterpret_cast<const float4*>(gamma)[t];
    float4 bv = reinterpret_cast<const float4*>(beta)[t];
    ushort4 o;
    o.x = f2bf((v.x - mean) * inv * gv.x + bv.x);
    o.y = f2bf((v.y - mean) * inv * gv.y + bv.y);
    o.z = f2bf((v.z - mean) * inv * gv.z + bv.z);
    o.w = f2bf((v.w - mean) * inv * gv.w + bv.w);
    reinterpret_cast<ushort4*>(out + (size_t)row * EMB)[t] = o;
}

// ---------------- GEMM: C[M][N] = A[M][K] (bf16) x Bt[N][K] (bf16) ----------------
// m97 structure: global_load_lds width-16 staging into linear [128][64] LDS.
// EPI 0: bf16 out.  EPI 1: f32 out = acc + bias[n] + resid.  EPI 2: bf16 gelu(acc+bias).
// EPI 4: fused QKV: n<1024 -> Q, n<2048 -> K, else V transposed (Cout2/Cout3).
template <int EPI>
__global__ __launch_bounds__(256) void gemm_bf16(
    const u16* __restrict__ A, const u16* __restrict__ B, void* __restrict__ Cout,
    const float* __restrict__ bias, const float* __restrict__ resid,
    void* __restrict__ Cout2, void* __restrict__ Cout3,
    int M, int N, int K) {
    __shared__ u16 As[128 * 64];
    __shared__ u16 Bs[128 * 64];
    int tm = blockIdx.x * 128;
    int tn = blockIdx.y * 128;
    int t = threadIdx.x;
    int lane = t & 63, wid = t >> 6;
    int wr = (wid >> 1) * 64, wc = (wid & 1) * 64;
    int l15 = lane & 15, g = lane >> 4;
    const u16* Abase = A + (size_t)tm * K;
    const u16* Bbase = B + (size_t)tn * K;
    f32x4 acc[4][4] = {};
    for (int k0 = 0; k0 < K; k0 += 64) {
        __syncthreads();
#pragma unroll
        for (int p = 0; p < 4; ++p) {
            int chunk = (wid * 4 + p) * 64 + lane;   // 16B chunk id, 0..1023
            int row = chunk >> 3, c8 = (chunk & 7) * 8;
            gload16(Abase + (size_t)row * K + k0 + c8, &As[(wid * 4 + p) * 512]);
            gload16(Bbase + (size_t)row * K + k0 + c8, &Bs[(wid * 4 + p) * 512]);
        }
        __syncthreads();
#pragma unroll
        for (int kc = 0; kc < 2; ++kc) {
            int ko = kc * 32 + g * 8;
            bf16x8 af[4], bfr[4];
#pragma unroll
            for (int i = 0; i < 4; ++i)
                af[i] = *reinterpret_cast<const bf16x8*>(&As[(wr + i * 16 + l15) * 64 + ko]);
#pragma unroll
            for (int j = 0; j < 4; ++j)
                bfr[j] = *reinterpret_cast<const bf16x8*>(&Bs[(wc + j * 16 + l15) * 64 + ko]);
#pragma unroll
            for (int i = 0; i < 4; ++i)
#pragma unroll
                for (int j = 0; j < 4; ++j)
                    acc[i][j] = __builtin_amdgcn_mfma_f32_16x16x32_bf16(af[i], bfr[j], acc[i][j], 0, 0, 0);
        }
    }
    int mb = tm + wr + g * 4;
    int nb = tn + wc + l15;
#pragma unroll
    for (int i = 0; i < 4; ++i) {
#pragma unroll
        for (int j = 0; j < 4; ++j) {
            int n = nb + j * 16;
#pragma unroll
            for (int r = 0; r < 4; ++r) {
                int m = mb + i * 16 + r;
                float val = acc[i][j][r];
                if constexpr (EPI == 0) {
                    ((u16*)Cout)[(size_t)m * N + n] = f2bf(val);
                } else if constexpr (EPI == 1) {
                    ((float*)Cout)[(size_t)m * N + n] =
                        val + bias[n] + resid[(size_t)m * N + n];
                } else if constexpr (EPI == 2) {
                    float xg = val + bias[n];
                    float x3 = xg + 0.044715f * xg * xg * xg;
                    float tz = 0.7978845608028654f * x3;
                    float th = 1.0f - 2.0f / (1.0f + __expf(2.0f * tz));
                    ((u16*)Cout)[(size_t)m * N + n] = f2bf(0.5f * xg * (1.0f + th));
                } else {  // EPI 4: fused QKV epilogue
                    if (n < 1024) {
                        ((u16*)Cout)[(size_t)m * 1024 + n] = f2bf(val);
                    } else if (n < 2048) {
                        ((u16*)Cout2)[(size_t)m * 1024 + (n - 1024)] = f2bf(val);
                    } else {
                        int bb = m >> 11, ss = m & 2047;
                        ((u16*)Cout3)[((size_t)(bb * EMB + (n - 2048))) * SEQ + ss] = f2bf(val);
                    }
                }
            }
        }
    }
}

// ---------------- Flash attention (causal), bf16 MFMA ----------------
// One wave (64 threads) per block, 32 q-rows per wave, heavy-first dispatch.
// Qb, Kb: [4096][1024] bf16 (row = b*2048+s, col = h*64+d)
// Vt: [2][1024][2048] bf16 (Vt[b][h*64+d][s]); ctx: [4096][1024] bf16
__global__ __launch_bounds__(64) void attn_kernel(
    const u16* __restrict__ Qb, const u16* __restrict__ Kb,
    const u16* __restrict__ Vt, u16* __restrict__ ctx) {
    __shared__ u16 P_lds[32][72];
    int bh = blockIdx.x;
    int b = bh >> 4, h = bh & 15;
    int qc = 63 - (int)blockIdx.y;  // heavy chunks dispatch first
    int lane = threadIdx.x;
    int l15 = lane & 15, g = lane >> 4;
    int qbase = qc * 32;

    bf16x8 qf[2][2];
#pragma unroll
    for (int qt = 0; qt < 2; ++qt)
#pragma unroll
        for (int kc = 0; kc < 2; ++kc)
            qf[qt][kc] = *reinterpret_cast<const bf16x8*>(
                Qb + (size_t)(b * SEQ + qbase + qt * 16 + l15) * EMB + h * 64 + kc * 32 + g * 8);

    f32x4 ctx_acc[2][4] = {};
    float mrun[2] = {-1e30f, -1e30f};
    float lrun[2] = {0.f, 0.f};
    int nkt = qc / 2 + 1;

    for (int kt = 0; kt < nkt; ++kt) {
        int k0 = kt * 64;
        // S^T = K . Q^T  (sacc[ktile][qt]: row=key=g*4+r, col=q=l15)
        f32x4 sacc[4][2] = {};
#pragma unroll
        for (int kc = 0; kc < 2; ++kc) {
#pragma unroll
            for (int ktile = 0; ktile < 4; ++ktile) {
                bf16x8 kf = *reinterpret_cast<const bf16x8*>(
                    Kb + (size_t)(b * SEQ + k0 + ktile * 16 + l15) * EMB + h * 64 + kc * 32 + g * 8);
#pragma unroll
                for (int qt = 0; qt < 2; ++qt)
                    sacc[ktile][qt] = __builtin_amdgcn_mfma_f32_16x16x32_bf16(
                        kf, qf[qt][kc], sacc[ktile][qt], 0, 0, 0);
            }
        }
#pragma unroll
        for (int qt = 0; qt < 2; ++qt) {
            int q = qbase + qt * 16 + l15;
            float sv[16];
            float tmax = -1e30f;
#pragma unroll
            for (int ktile = 0; ktile < 4; ++ktile)
#pragma unroll
                for (int r = 0; r < 4; ++r) {
                    int key = k0 + ktile * 16 + g * 4 + r;
                    float sx = sacc[ktile][qt][r] * 0.125f;
                    if (key > q) sx = -1e30f;
                    sv[ktile * 4 + r] = sx;
                    tmax = fmaxf(tmax, sx);
                }
            tmax = fmaxf(tmax, __shfl_xor(tmax, 16));
            tmax = fmaxf(tmax, __shfl_xor(tmax, 32));
            float mnew = fmaxf(mrun[qt], tmax);
            float corr = __expf(mrun[qt] - mnew);
            mrun[qt] = mnew;
            float psum = 0.f;
#pragma unroll
            for (int idx = 0; idx < 16; ++idx) {
                float p = __expf(sv[idx] - mnew);
                sv[idx] = p;
                psum += p;
            }
            lrun[qt] = lrun[qt] * corr + psum;
            float corr4[4];
#pragma unroll
            for (int r = 0; r < 4; ++r) corr4[r] = __shfl(corr, g * 4 + r);
#pragma unroll
            for (int dt = 0; dt < 4; ++dt)
#pragma unroll
                for (int r = 0; r < 4; ++r) ctx_acc[qt][dt][r] *= corr4[r];
#pragma unroll
            for (int ktile = 0; ktile < 4; ++ktile) {
                ushort4 pk;
                pk.x = f2bf(sv[ktile * 4 + 0]);
                pk.y = f2bf(sv[ktile * 4 + 1]);
                pk.z = f2bf(sv[ktile * 4 + 2]);
                pk.w = f2bf(sv[ktile * 4 + 3]);
                *reinterpret_cast<ushort4*>(&P_lds[qt * 16 + l15][ktile * 16 + g * 4]) = pk;
            }
        }
        asm volatile("s_waitcnt lgkmcnt(0)" ::: "memory");
        // ctx += P . V
#pragma unroll
        for (int kc = 0; kc < 2; ++kc) {
            bf16x8 pf[2];
#pragma unroll
            for (int qt = 0; qt < 2; ++qt)
                pf[qt] = *reinterpret_cast<const bf16x8*>(&P_lds[qt * 16 + l15][kc * 32 + g * 8]);
#pragma unroll
            for (int dt = 0; dt < 4; ++dt) {
                bf16x8 vf = *reinterpret_cast<const bf16x8*>(
                    Vt + (size_t)(b * EMB + h * 64 + dt * 16 + l15) * SEQ + k0 + kc * 32 + g * 8);
#pragma unroll
                for (int qt = 0; qt < 2; ++qt)
                    ctx_acc[qt][dt] = __builtin_amdgcn_mfma_f32_16x16x32_bf16(
                        pf[qt], vf, ctx_acc[qt][dt], 0, 0, 0);
            }
        }
    }
#pragma unroll
    for (int qt = 0; qt < 2; ++qt) {
        float lsum = lrun[qt];
        lsum += __shfl_xor(lsum, 16);
        lsum += __shfl_xor(lsum, 32);
        float d4[4];
#pragma unroll
        for (int r = 0; r < 4; ++r) d4[r] = __shfl(lsum, g * 4 + r);
#pragma unroll
        for (int dt = 0; dt < 4; ++dt)
#pragma unroll
            for (int r = 0; r < 4; ++r) {
                int q = qbase + qt * 16 + g * 4 + r;
                int d = h * 64 + dt * 16 + l15;
                ctx[(size_t)(b * SEQ + q) * EMB + d] = f2bf(ctx_acc[qt][dt][r] / d4[r]);
            }
    }
}

extern "C" void kernel_launch(void* const* d_in, const int* in_sizes, int n_in,
                              void* d_out, int out_size, void* d_ws, size_t ws_size,
                              hipStream_t stream) {
    const float* x    = (const float*)d_in[0];
    const float* Wq   = (const float*)d_in[1];
    const float* Wk   = (const float*)d_in[2];
    const float* Wv   = (const float*)d_in[3];
    const float* Wo   = (const float*)d_in[4];
    const float* bo   = (const float*)d_in[5];
    const float* ln1g = (const float*)d_in[6];
    const float* ln1b = (const float*)d_in[7];
    const float* ln2g = (const float*)d_in[8];
    const float* ln2b = (const float*)d_in[9];
    const float* W1   = (const float*)d_in[10];
    const float* b1   = (const float*)d_in[11];
    const float* W2   = (const float*)d_in[12];
    const float* b2   = (const float*)d_in[13];

    char* ws = (char*)d_ws;
    size_t off = 0;
    auto alloc = [&](size_t bytes) {
        void* p = ws + off;
        off += (bytes + 255) & ~(size_t)255;
        return p;
    };
    u16* h1     = (u16*)alloc((size_t)ROWS * EMB * 2);
    u16* Wqkvt  = (u16*)alloc((size_t)3 * EMB * EMB * 2);  // [3072][1024]
    u16* Wot    = (u16*)alloc((size_t)EMB * EMB * 2);
    u16* W1t    = (u16*)alloc((size_t)FF * EMB * 2);   // [4096][1024]
    u16* W2t    = (u16*)alloc((size_t)EMB * FF * 2);   // [1024][4096]
    u16* Qb     = (u16*)alloc((size_t)ROWS * EMB * 2);
    u16* Kb     = (u16*)alloc((size_t)ROWS * EMB * 2);
    u16* Vtb    = (u16*)alloc((size_t)BATCH * EMB * SEQ * 2);
    u16* ctxb   = (u16*)alloc((size_t)ROWS * EMB * 2);
    float* x2   = (float*)alloc((size_t)ROWS * EMB * 4);
    u16* h2     = (u16*)alloc((size_t)ROWS * EMB * 2);
    u16* ff1    = (u16*)alloc((size_t)ROWS * FF * 2);

    u16* Wqt = Wqkvt;                    // rows 0..1023
    u16* Wkt = Wqkvt + (size_t)EMB * EMB;    // rows 1024..2047
    u16* Wvt = Wqkvt + (size_t)2 * EMB * EMB;  // rows 2048..3071

    // weight transposes (f32 [R][C] -> bf16 [C][R]); grid (C/32, R/32)
    transpose_f32_to_bf16<<<dim3(32, 32), 256, 0, stream>>>(Wq, Wqt, EMB, EMB);
    transpose_f32_to_bf16<<<dim3(32, 32), 256, 0, stream>>>(Wk, Wkt, EMB, EMB);
    transpose_f32_to_bf16<<<dim3(32, 32), 256, 0, stream>>>(Wv, Wvt, EMB, EMB);
    transpose_f32_to_bf16<<<dim3(32, 32), 256, 0, stream>>>(Wo, Wot, EMB, EMB);
    transpose_f32_to_bf16<<<dim3(128, 32), 256, 0, stream>>>(W1, W1t, EMB, FF);
    transpose_f32_to_bf16<<<dim3(32, 128), 256, 0, stream>>>(W2, W2t, FF, EMB);

    ln_kernel<<<ROWS, 256, 0, stream>>>(x, ln1g, ln1b, h1);

    // fused QKV: C[4096][3072] split into Qb, Kb, Vt
    gemm_bf16<4><<<dim3(32, 24), 256, 0, stream>>>(h1, Wqkvt, Qb, nullptr, nullptr,
                                                   Kb, Vtb, ROWS, 3072, EMB);

    attn_kernel<<<dim3(32, 64), 64, 0, stream>>>(Qb, Kb, Vtb, ctxb);

    gemm_bf16<1><<<dim3(32, 8), 256, 0, stream>>>(ctxb, Wot, x2, bo, x,
                                                  nullptr, nullptr, ROWS, EMB, EMB);

    ln_kernel<<<ROWS, 256, 0, stream>>>(x2, ln2g, ln2b, h2);

    gemm_bf16<2><<<dim3(32, 32), 256, 0, stream>>>(h2, W1t, ff1, b1, nullptr,
                                                   nullptr, nullptr, ROWS, FF, EMB);
    gemm_bf16<1><<<dim3(32, 8), 256, 0, stream>>>(ff1, W2t, (float*)d_out, b2, x2,
                                                  nullptr, nullptr, ROWS, EMB, FF);
}

// Round 5
// 437.144 us; speedup vs baseline: 1.1003x; 1.1003x over previous
//
#include <hip/hip_runtime.h>

typedef __bf16 bf16x8 __attribute__((ext_vector_type(8)));
typedef float f32x4 __attribute__((ext_vector_type(4)));
typedef unsigned short u16;

#define EMB 1024
#define SEQ 2048
#define BATCH 2
#define HEADS 16
#define HEAD_DIM 64
#define FF 4096
#define ROWS (BATCH * SEQ)  // 4096

static __device__ __forceinline__ u16 f2bf(float f) {
    unsigned int u = __builtin_bit_cast(unsigned int, f);
    unsigned int r = (u + 0x7FFFu + ((u >> 16) & 1u)) >> 16;
    return (u16)r;
}

// pack two f32 -> two bf16 (truncation) in ONE v_perm_b32: result = {hi16(a), hi16(b)}
static __device__ __forceinline__ unsigned int pack_bf_trunc(float a, float b) {
    return __builtin_amdgcn_perm(__builtin_bit_cast(unsigned int, a),
                                 __builtin_bit_cast(unsigned int, b), 0x07060302u);
}

// async global->LDS, 16B per lane. LDS dest must be wave-uniform base (HW adds lane*16).
static __device__ __forceinline__ void gload16(const u16* g, u16* l) {
    __builtin_amdgcn_global_load_lds(
        (const __attribute__((address_space(1))) unsigned int*)(const void*)g,
        (__attribute__((address_space(3))) unsigned int*)(void*)l, 16, 0, 0);
}

// ---------------- transpose + convert: f32 [R][C] -> bf16 [C][R] ----------------
__global__ __launch_bounds__(256) void transpose_f32_to_bf16(
    const float* __restrict__ in, u16* __restrict__ out, int R, int C) {
    __shared__ float tile[32][33];
    int c0 = blockIdx.x * 32, r0 = blockIdx.y * 32;
    int tx = threadIdx.x & 31, ty = threadIdx.x >> 5;  // ty: 0..7
#pragma unroll
    for (int i = 0; i < 32; i += 8)
        tile[ty + i][tx] = in[(size_t)(r0 + ty + i) * C + c0 + tx];
    __syncthreads();
#pragma unroll
    for (int i = 0; i < 32; i += 8)
        out[(size_t)(c0 + ty + i) * R + r0 + tx] = f2bf(tile[tx][ty + i]);
}

// fused 4x square (1024x1024) weight transpose, z selects the weight
__global__ __launch_bounds__(256) void transpose4_f32_to_bf16(
    const float* __restrict__ s0, const float* __restrict__ s1,
    const float* __restrict__ s2, const float* __restrict__ s3,
    u16* __restrict__ d0, u16* __restrict__ d1,
    u16* __restrict__ d2, u16* __restrict__ d3) {
    __shared__ float tile[32][33];
    const float* in;
    u16* out;
    switch (blockIdx.z) {
        case 0: in = s0; out = d0; break;
        case 1: in = s1; out = d1; break;
        case 2: in = s2; out = d2; break;
        default: in = s3; out = d3; break;
    }
    int c0 = blockIdx.x * 32, r0 = blockIdx.y * 32;
    int tx = threadIdx.x & 31, ty = threadIdx.x >> 5;
#pragma unroll
    for (int i = 0; i < 32; i += 8)
        tile[ty + i][tx] = in[(size_t)(r0 + ty + i) * EMB + c0 + tx];
    __syncthreads();
#pragma unroll
    for (int i = 0; i < 32; i += 8)
        out[(size_t)(c0 + ty + i) * EMB + r0 + tx] = f2bf(tile[tx][ty + i]);
}

// ---------------- LayerNorm: f32 [rows][1024] -> bf16 ----------------
__global__ __launch_bounds__(256) void ln_kernel(
    const float* __restrict__ x, const float* __restrict__ gamma,
    const float* __restrict__ beta, u16* __restrict__ out) {
    int row = blockIdx.x;
    int t = threadIdx.x;
    float4 v = reinterpret_cast<const float4*>(x + (size_t)row * EMB)[t];
    float s = v.x + v.y + v.z + v.w;
    float s2 = v.x * v.x + v.y * v.y + v.z * v.z + v.w * v.w;
#pragma unroll
    for (int off = 1; off < 64; off <<= 1) {
        s += __shfl_xor(s, off);
        s2 += __shfl_xor(s2, off);
    }
    __shared__ float sm[8];
    int wid = t >> 6;
    if ((t & 63) == 0) { sm[wid] = s; sm[wid + 4] = s2; }
    __syncthreads();
    s = sm[0] + sm[1] + sm[2] + sm[3];
    s2 = sm[4] + sm[5] + sm[6] + sm[7];
    float mean = s * (1.0f / EMB);
    float var = s2 * (1.0f / EMB) - mean * mean;
    float inv = rsqrtf(var + 1e-5f);
    float4 gv = reinterpret_cast<const float4*>(gamma)[t];
    float4 bv = reinterpret_cast<const float4*>(beta)[t];
    ushort4 o;
    o.x = f2bf((v.x - mean) * inv * gv.x + bv.x);
    o.y = f2bf((v.y - mean) * inv * gv.y + bv.y);
    o.z = f2bf((v.z - mean) * inv * gv.z + bv.z);
    o.w = f2bf((v.w - mean) * inv * gv.w + bv.w);
    reinterpret_cast<ushort4*>(out + (size_t)row * EMB)[t] = o;
}

// ---------------- GEMM: C[M][N] = A[M][K] (bf16) x Bt[N][K] (bf16) ----------------
// m97 structure: global_load_lds width-16 staging into linear [128][64] LDS.
// EPI 0: bf16 out.  EPI 1: f32 out = acc + bias[n] + resid.  EPI 2: bf16 gelu(acc+bias).
// EPI 4: fused QKV: n<1024 -> Q, n<2048 -> K, else V transposed (Cout2/Cout3).
template <int EPI>
__global__ __launch_bounds__(256) void gemm_bf16(
    const u16* __restrict__ A, const u16* __restrict__ B, void* __restrict__ Cout,
    const float* __restrict__ bias, const float* __restrict__ resid,
    void* __restrict__ Cout2, void* __restrict__ Cout3,
    int M, int N, int K) {
    __shared__ u16 As[128 * 64];
    __shared__ u16 Bs[128 * 64];
    int tm = blockIdx.x * 128;
    int tn = blockIdx.y * 128;
    int t = threadIdx.x;
    int lane = t & 63, wid = t >> 6;
    int wr = (wid >> 1) * 64, wc = (wid & 1) * 64;
    int l15 = lane & 15, g = lane >> 4;
    const u16* Abase = A + (size_t)tm * K;
    const u16* Bbase = B + (size_t)tn * K;
    f32x4 acc[4][4] = {};
    for (int k0 = 0; k0 < K; k0 += 64) {
        __syncthreads();
#pragma unroll
        for (int p = 0; p < 4; ++p) {
            int chunk = (wid * 4 + p) * 64 + lane;   // 16B chunk id, 0..1023
            int row = chunk >> 3, c8 = (chunk & 7) * 8;
            gload16(Abase + (size_t)row * K + k0 + c8, &As[(wid * 4 + p) * 512]);
            gload16(Bbase + (size_t)row * K + k0 + c8, &Bs[(wid * 4 + p) * 512]);
        }
        __syncthreads();
#pragma unroll
        for (int kc = 0; kc < 2; ++kc) {
            int ko = kc * 32 + g * 8;
            bf16x8 af[4], bfr[4];
#pragma unroll
            for (int i = 0; i < 4; ++i)
                af[i] = *reinterpret_cast<const bf16x8*>(&As[(wr + i * 16 + l15) * 64 + ko]);
#pragma unroll
            for (int j = 0; j < 4; ++j)
                bfr[j] = *reinterpret_cast<const bf16x8*>(&Bs[(wc + j * 16 + l15) * 64 + ko]);
#pragma unroll
            for (int i = 0; i < 4; ++i)
#pragma unroll
                for (int j = 0; j < 4; ++j)
                    acc[i][j] = __builtin_amdgcn_mfma_f32_16x16x32_bf16(af[i], bfr[j], acc[i][j], 0, 0, 0);
        }
    }
    int mb = tm + wr + g * 4;
    int nb = tn + wc + l15;
#pragma unroll
    for (int i = 0; i < 4; ++i) {
#pragma unroll
        for (int j = 0; j < 4; ++j) {
            int n = nb + j * 16;
#pragma unroll
            for (int r = 0; r < 4; ++r) {
                int m = mb + i * 16 + r;
                float val = acc[i][j][r];
                if constexpr (EPI == 0) {
                    ((u16*)Cout)[(size_t)m * N + n] = f2bf(val);
                } else if constexpr (EPI == 1) {
                    ((float*)Cout)[(size_t)m * N + n] =
                        val + bias[n] + resid[(size_t)m * N + n];
                } else if constexpr (EPI == 2) {
                    float xg = val + bias[n];
                    float x3 = xg + 0.044715f * xg * xg * xg;
                    float tz = 0.7978845608028654f * x3;
                    float th = 1.0f - 2.0f / (1.0f + __expf(2.0f * tz));
                    ((u16*)Cout)[(size_t)m * N + n] = f2bf(0.5f * xg * (1.0f + th));
                } else {  // EPI 4: fused QKV epilogue
                    if (n < 1024) {
                        ((u16*)Cout)[(size_t)m * 1024 + n] = f2bf(val);
                    } else if (n < 2048) {
                        ((u16*)Cout2)[(size_t)m * 1024 + (n - 1024)] = f2bf(val);
                    } else {
                        int bb = m >> 11, ss = m & 2047;
                        ((u16*)Cout3)[((size_t)(bb * EMB + (n - 2048))) * SEQ + ss] = f2bf(val);
                    }
                }
            }
        }
    }
}

// ---------------- Flash attention (causal), bf16 MFMA ----------------
// One wave per block, 32 q-rows, KVBLK=64. Q pre-scaled by 1/8.
// Issue-early V loads + K tile prefetch (register double-buffer).
// Defer-max online softmax (THR=8); mask only on the final (diagonal) k-tile.
// Qb, Kb: [4096][1024] bf16; Vt: [2][1024][2048] bf16; ctx: [4096][1024] bf16
__global__ __launch_bounds__(64) void attn_kernel(
    const u16* __restrict__ Qb, const u16* __restrict__ Kb,
    const u16* __restrict__ Vt, u16* __restrict__ ctx) {
    __shared__ u16 P_lds[32][72];
    int bh = blockIdx.x;
    int b = bh >> 4, h = bh & 15;
    int qc = 63 - (int)blockIdx.y;  // heavy chunks dispatch first
    int lane = threadIdx.x;
    int l15 = lane & 15, g = lane >> 4;
    int qbase = qc * 32;

    const u16* Qrow = Qb + (size_t)(b * SEQ) * EMB + h * 64;
    const u16* Krow = Kb + (size_t)(b * SEQ) * EMB + h * 64;
    const u16* Vrow = Vt + (size_t)(b * EMB + h * 64) * SEQ;

    // Q fragments, pre-scaled by 0.125 (exact power of two -> no bf16 error)
    bf16x8 qf[2][2];
#pragma unroll
    for (int qt = 0; qt < 2; ++qt)
#pragma unroll
        for (int kc = 0; kc < 2; ++kc) {
            bf16x8 v = *reinterpret_cast<const bf16x8*>(
                Qrow + (size_t)(qbase + qt * 16 + l15) * EMB + kc * 32 + g * 8);
            bf16x8 sv;
#pragma unroll
            for (int e = 0; e < 8; ++e) sv[e] = (__bf16)((float)v[e] * 0.125f);
            qf[qt][kc] = sv;
        }

    f32x4 ctx_acc[2][4] = {};
    float mrun[2] = {-1e30f, -1e30f};
    float lrun[2] = {0.f, 0.f};
    int nkt = qc / 2 + 1;

    // preload K tile 0 (idx = kc*4 + ktile)
    bf16x8 kcur[8], knxt[8];
#pragma unroll
    for (int i = 0; i < 8; ++i) {
        int kc = i >> 2, ktile = i & 3;
        kcur[i] = *reinterpret_cast<const bf16x8*>(
            Krow + (size_t)(ktile * 16 + l15) * EMB + kc * 32 + g * 8);
    }

    for (int kt = 0; kt < nkt; ++kt) {
        int k0 = kt * 64;
        bool last = (kt == nkt - 1);
        // issue V loads for THIS tile now; consumed after softmax (latency hidden)
        bf16x8 vf[8];  // idx = kc*4 + dt
#pragma unroll
        for (int i = 0; i < 8; ++i) {
            int kc = i >> 2, dt = i & 3;
            vf[i] = *reinterpret_cast<const bf16x8*>(
                Vrow + (size_t)(dt * 16 + l15) * SEQ + k0 + kc * 32 + g * 8);
        }
        // S^T = K . Q^T  (sacc[ktile][qt]: row=key=g*4+r, col=q=l15)
        f32x4 sacc[4][2] = {};
#pragma unroll
        for (int kc = 0; kc < 2; ++kc)
#pragma unroll
            for (int ktile = 0; ktile < 4; ++ktile)
#pragma unroll
                for (int qt = 0; qt < 2; ++qt)
                    sacc[ktile][qt] = __builtin_amdgcn_mfma_f32_16x16x32_bf16(
                        kcur[kc * 4 + ktile], qf[qt][kc], sacc[ktile][qt], 0, 0, 0);
        // prefetch NEXT K tile; consumed next iteration (latency hidden under softmax+PV)
        if (kt + 1 < nkt) {
#pragma unroll
            for (int i = 0; i < 8; ++i) {
                int kc = i >> 2, ktile = i & 3;
                knxt[i] = *reinterpret_cast<const bf16x8*>(
                    Krow + (size_t)(k0 + 64 + ktile * 16 + l15) * EMB + kc * 32 + g * 8);
            }
        }
#pragma unroll
        for (int qt = 0; qt < 2; ++qt) {
            float sv[16];
            float tmax = -1e30f;
            if (last) {
                int q = qbase + qt * 16 + l15;
#pragma unroll
                for (int ktile = 0; ktile < 4; ++ktile)
#pragma unroll
                    for (int r = 0; r < 4; ++r) {
                        int key = k0 + ktile * 16 + g * 4 + r;
                        float sx = (key > q) ? -1e30f : sacc[ktile][qt][r];
                        sv[ktile * 4 + r] = sx;
                        tmax = fmaxf(tmax, sx);
                    }
            } else {
#pragma unroll
                for (int ktile = 0; ktile < 4; ++ktile)
#pragma unroll
                    for (int r = 0; r < 4; ++r) {
                        float sx = sacc[ktile][qt][r];
                        sv[ktile * 4 + r] = sx;
                        tmax = fmaxf(tmax, sx);
                    }
            }
            tmax = fmaxf(tmax, __shfl_xor(tmax, 16));
            tmax = fmaxf(tmax, __shfl_xor(tmax, 32));
            // defer-max: only rescale when the running max grew by >8
            if (!__all(tmax <= mrun[qt] + 8.0f)) {
                float mnew = fmaxf(mrun[qt], tmax);
                float corr = __expf(mrun[qt] - mnew);
                mrun[qt] = mnew;
                lrun[qt] *= corr;
                float corr4[4];
#pragma unroll
                for (int r = 0; r < 4; ++r) corr4[r] = __shfl(corr, g * 4 + r);
#pragma unroll
                for (int dt = 0; dt < 4; ++dt)
#pragma unroll
                    for (int r = 0; r < 4; ++r) ctx_acc[qt][dt][r] *= corr4[r];
            }
            float m = mrun[qt];
            float psum = 0.f;
#pragma unroll
            for (int idx = 0; idx < 16; ++idx) {
                float p = __expf(sv[idx] - m);
                sv[idx] = p;
                psum += p;
            }
            lrun[qt] += psum;
            // pack P -> bf16 (truncation) with one v_perm per pair
#pragma unroll
            for (int ktile = 0; ktile < 4; ++ktile) {
                uint2 w;
                w.x = pack_bf_trunc(sv[ktile * 4 + 1], sv[ktile * 4 + 0]);
                w.y = pack_bf_trunc(sv[ktile * 4 + 3], sv[ktile * 4 + 2]);
                *reinterpret_cast<uint2*>(&P_lds[qt * 16 + l15][ktile * 16 + g * 4]) = w;
            }
        }
        asm volatile("s_waitcnt lgkmcnt(0)" ::: "memory");
        // ctx += P . V
#pragma unroll
        for (int kc = 0; kc < 2; ++kc) {
            bf16x8 pf[2];
#pragma unroll
            for (int qt = 0; qt < 2; ++qt)
                pf[qt] = *reinterpret_cast<const bf16x8*>(&P_lds[qt * 16 + l15][kc * 32 + g * 8]);
#pragma unroll
            for (int dt = 0; dt < 4; ++dt)
#pragma unroll
                for (int qt = 0; qt < 2; ++qt)
                    ctx_acc[qt][dt] = __builtin_amdgcn_mfma_f32_16x16x32_bf16(
                        pf[qt], vf[kc * 4 + dt], ctx_acc[qt][dt], 0, 0, 0);
        }
#pragma unroll
        for (int i = 0; i < 8; ++i) kcur[i] = knxt[i];
    }
#pragma unroll
    for (int qt = 0; qt < 2; ++qt) {
        float lsum = lrun[qt];
        lsum += __shfl_xor(lsum, 16);
        lsum += __shfl_xor(lsum, 32);
        float d4[4];
#pragma unroll
        for (int r = 0; r < 4; ++r) d4[r] = __shfl(lsum, g * 4 + r);
#pragma unroll
        for (int dt = 0; dt < 4; ++dt)
#pragma unroll
            for (int r = 0; r < 4; ++r) {
                int q = qbase + qt * 16 + g * 4 + r;
                int d = h * 64 + dt * 16 + l15;
                ctx[(size_t)(b * SEQ + q) * EMB + d] = f2bf(ctx_acc[qt][dt][r] / d4[r]);
            }
    }
}

extern "C" void kernel_launch(void* const* d_in, const int* in_sizes, int n_in,
                              void* d_out, int out_size, void* d_ws, size_t ws_size,
                              hipStream_t stream) {
    const float* x    = (const float*)d_in[0];
    const float* Wq   = (const float*)d_in[1];
    const float* Wk   = (const float*)d_in[2];
    const float* Wv   = (const float*)d_in[3];
    const float* Wo   = (const float*)d_in[4];
    const float* bo   = (const float*)d_in[5];
    const float* ln1g = (const float*)d_in[6];
    const float* ln1b = (const float*)d_in[7];
    const float* ln2g = (const float*)d_in[8];
    const float* ln2b = (const float*)d_in[9];
    const float* W1   = (const float*)d_in[10];
    const float* b1   = (const float*)d_in[11];
    const float* W2   = (const float*)d_in[12];
    const float* b2   = (const float*)d_in[13];

    char* ws = (char*)d_ws;
    size_t off = 0;
    auto alloc = [&](size_t bytes) {
        void* p = ws + off;
        off += (bytes + 255) & ~(size_t)255;
        return p;
    };
    u16* h1     = (u16*)alloc((size_t)ROWS * EMB * 2);
    u16* Wqkvt  = (u16*)alloc((size_t)3 * EMB * EMB * 2);  // [3072][1024]
    u16* Wot    = (u16*)alloc((size_t)EMB * EMB * 2);
    u16* W1t    = (u16*)alloc((size_t)FF * EMB * 2);   // [4096][1024]
    u16* W2t    = (u16*)alloc((size_t)EMB * FF * 2);   // [1024][4096]
    u16* Qb     = (u16*)alloc((size_t)ROWS * EMB * 2);
    u16* Kb     = (u16*)alloc((size_t)ROWS * EMB * 2);
    u16* Vtb    = (u16*)alloc((size_t)BATCH * EMB * SEQ * 2);
    u16* ctxb   = (u16*)alloc((size_t)ROWS * EMB * 2);
    float* x2   = (float*)alloc((size_t)ROWS * EMB * 4);
    u16* h2     = (u16*)alloc((size_t)ROWS * EMB * 2);
    u16* ff1    = (u16*)alloc((size_t)ROWS * FF * 2);

    u16* Wqt = Wqkvt;                          // rows 0..1023
    u16* Wkt = Wqkvt + (size_t)EMB * EMB;      // rows 1024..2047
    u16* Wvt = Wqkvt + (size_t)2 * EMB * EMB;  // rows 2048..3071

    // fused square-weight transposes + the two FF transposes
    transpose4_f32_to_bf16<<<dim3(32, 32, 4), 256, 0, stream>>>(
        Wq, Wk, Wv, Wo, Wqt, Wkt, Wvt, Wot);
    transpose_f32_to_bf16<<<dim3(128, 32), 256, 0, stream>>>(W1, W1t, EMB, FF);
    transpose_f32_to_bf16<<<dim3(32, 128), 256, 0, stream>>>(W2, W2t, FF, EMB);

    ln_kernel<<<ROWS, 256, 0, stream>>>(x, ln1g, ln1b, h1);

    // fused QKV: C[4096][3072] split into Qb, Kb, Vt
    gemm_bf16<4><<<dim3(32, 24), 256, 0, stream>>>(h1, Wqkvt, Qb, nullptr, nullptr,
                                                   Kb, Vtb, ROWS, 3072, EMB);

    attn_kernel<<<dim3(32, 64), 64, 0, stream>>>(Qb, Kb, Vtb, ctxb);

    gemm_bf16<1><<<dim3(32, 8), 256, 0, stream>>>(ctxb, Wot, x2, bo, x,
                                                  nullptr, nullptr, ROWS, EMB, EMB);

    ln_kernel<<<ROWS, 256, 0, stream>>>(x2, ln2g, ln2b, h2);

    gemm_bf16<2><<<dim3(32, 32), 256, 0, stream>>>(h2, W1t, ff1, b1, nullptr,
                                                   nullptr, nullptr, ROWS, FF, EMB);
    gemm_bf16<1><<<dim3(32, 8), 256, 0, stream>>>(ff1, W2t, (float*)d_out, b2, x2,
                                                  nullptr, nullptr, ROWS, EMB, FF);
}

// Round 6
// 415.204 us; speedup vs baseline: 1.1585x; 1.0528x over previous
//
#include <hip/hip_runtime.h>

typedef __bf16 bf16x8 __attribute__((ext_vector_type(8)));
typedef float f32x4 __attribute__((ext_vector_type(4)));
typedef unsigned short u16;

#define EMB 1024
#define SEQ 2048
#define BATCH 2
#define HEADS 16
#define HEAD_DIM 64
#define FF 4096
#define ROWS (BATCH * SEQ)  // 4096

static __device__ __forceinline__ u16 f2bf(float f) {
    unsigned int u = __builtin_bit_cast(unsigned int, f);
    unsigned int r = (u + 0x7FFFu + ((u >> 16) & 1u)) >> 16;
    return (u16)r;
}

// pack two f32 -> two bf16 (truncation) in ONE v_perm_b32: result = {hi16(a), hi16(b)}
static __device__ __forceinline__ unsigned int pack_bf_trunc(float a, float b) {
    return __builtin_amdgcn_perm(__builtin_bit_cast(unsigned int, a),
                                 __builtin_bit_cast(unsigned int, b), 0x07060302u);
}

// async global->LDS, 16B per lane. LDS dest must be wave-uniform base (HW adds lane*16).
static __device__ __forceinline__ void gload16(const u16* g, u16* l) {
    __builtin_amdgcn_global_load_lds(
        (const __attribute__((address_space(1))) unsigned int*)(const void*)g,
        (__attribute__((address_space(3))) unsigned int*)(void*)l, 16, 0, 0);
}

// ---------------- transpose + convert: f32 [R][C] -> bf16 [C][R] ----------------
__global__ __launch_bounds__(256) void transpose_f32_to_bf16(
    const float* __restrict__ in, u16* __restrict__ out, int R, int C) {
    __shared__ float tile[32][33];
    int c0 = blockIdx.x * 32, r0 = blockIdx.y * 32;
    int tx = threadIdx.x & 31, ty = threadIdx.x >> 5;  // ty: 0..7
#pragma unroll
    for (int i = 0; i < 32; i += 8)
        tile[ty + i][tx] = in[(size_t)(r0 + ty + i) * C + c0 + tx];
    __syncthreads();
#pragma unroll
    for (int i = 0; i < 32; i += 8)
        out[(size_t)(c0 + ty + i) * R + r0 + tx] = f2bf(tile[tx][ty + i]);
}

// fused 4x square (1024x1024) weight transpose, z selects the weight
__global__ __launch_bounds__(256) void transpose4_f32_to_bf16(
    const float* __restrict__ s0, const float* __restrict__ s1,
    const float* __restrict__ s2, const float* __restrict__ s3,
    u16* __restrict__ d0, u16* __restrict__ d1,
    u16* __restrict__ d2, u16* __restrict__ d3) {
    __shared__ float tile[32][33];
    const float* in;
    u16* out;
    switch (blockIdx.z) {
        case 0: in = s0; out = d0; break;
        case 1: in = s1; out = d1; break;
        case 2: in = s2; out = d2; break;
        default: in = s3; out = d3; break;
    }
    int c0 = blockIdx.x * 32, r0 = blockIdx.y * 32;
    int tx = threadIdx.x & 31, ty = threadIdx.x >> 5;
#pragma unroll
    for (int i = 0; i < 32; i += 8)
        tile[ty + i][tx] = in[(size_t)(r0 + ty + i) * EMB + c0 + tx];
    __syncthreads();
#pragma unroll
    for (int i = 0; i < 32; i += 8)
        out[(size_t)(c0 + ty + i) * EMB + r0 + tx] = f2bf(tile[tx][ty + i]);
}

// ---------------- LayerNorm: f32 [rows][1024] -> bf16 ----------------
__global__ __launch_bounds__(256) void ln_kernel(
    const float* __restrict__ x, const float* __restrict__ gamma,
    const float* __restrict__ beta, u16* __restrict__ out) {
    int row = blockIdx.x;
    int t = threadIdx.x;
    float4 v = reinterpret_cast<const float4*>(x + (size_t)row * EMB)[t];
    float s = v.x + v.y + v.z + v.w;
    float s2 = v.x * v.x + v.y * v.y + v.z * v.z + v.w * v.w;
#pragma unroll
    for (int off = 1; off < 64; off <<= 1) {
        s += __shfl_xor(s, off);
        s2 += __shfl_xor(s2, off);
    }
    __shared__ float sm[8];
    int wid = t >> 6;
    if ((t & 63) == 0) { sm[wid] = s; sm[wid + 4] = s2; }
    __syncthreads();
    s = sm[0] + sm[1] + sm[2] + sm[3];
    s2 = sm[4] + sm[5] + sm[6] + sm[7];
    float mean = s * (1.0f / EMB);
    float var = s2 * (1.0f / EMB) - mean * mean;
    float inv = rsqrtf(var + 1e-5f);
    float4 gv = reinterpret_cast<const float4*>(gamma)[t];
    float4 bv = reinterpret_cast<const float4*>(beta)[t];
    ushort4 o;
    o.x = f2bf((v.x - mean) * inv * gv.x + bv.x);
    o.y = f2bf((v.y - mean) * inv * gv.y + bv.y);
    o.z = f2bf((v.z - mean) * inv * gv.z + bv.z);
    o.w = f2bf((v.w - mean) * inv * gv.w + bv.w);
    reinterpret_cast<ushort4*>(out + (size_t)row * EMB)[t] = o;
}

// ---------------- GEMM: C[M][N] = A[M][K] (bf16) x Bt[N][K] (bf16) ----------------
// m97 structure: global_load_lds width-16 staging into linear [128|BN][64] LDS.
// Tile = 128 x BN. BN=128: 4 waves of 64x64 (acc 4x4). BN=64: 4 waves of 32x64 (acc 2x4)
//   -> 2x the blocks for N=1024 GEMMs (2 blocks/CU instead of 1: hides barrier drains).
// EPI 0: bf16 out.  EPI 1: f32 out = acc + bias[n] + resid.  EPI 2: bf16 gelu(acc+bias).
// EPI 4: fused QKV: n<1024 -> Q, n<2048 -> K, else V transposed (Cout2/Cout3).
template <int EPI, int BN>
__global__ __launch_bounds__(256) void gemm_bf16(
    const u16* __restrict__ A, const u16* __restrict__ B, void* __restrict__ Cout,
    const float* __restrict__ bias, const float* __restrict__ resid,
    void* __restrict__ Cout2, void* __restrict__ Cout3,
    int M, int N, int K) {
    __shared__ u16 As[128 * 64];
    __shared__ u16 Bs[BN * 64];
    constexpr int MI = (BN == 128) ? 4 : 2;  // 16-row frags per wave (rows)
    constexpr int BSW = BN / 32;             // B staging sweeps (A is always 4)
    int tm = blockIdx.x * 128;
    int tn = blockIdx.y * BN;
    int t = threadIdx.x;
    int lane = t & 63, wid = t >> 6;
    int wr, wc;
    if constexpr (BN == 128) { wr = (wid >> 1) * 64; wc = (wid & 1) * 64; }
    else { wr = wid * 32; wc = 0; }
    int l15 = lane & 15, g = lane >> 4;
    const u16* Abase = A + (size_t)tm * K;
    const u16* Bbase = B + (size_t)tn * K;
    f32x4 acc[MI][4] = {};
    for (int k0 = 0; k0 < K; k0 += 64) {
        __syncthreads();
#pragma unroll
        for (int p = 0; p < 4; ++p) {
            int chunk = (wid * 4 + p) * 64 + lane;   // 16B chunk id, 0..1023
            int row = chunk >> 3, c8 = (chunk & 7) * 8;
            gload16(Abase + (size_t)row * K + k0 + c8, &As[(wid * 4 + p) * 512]);
        }
#pragma unroll
        for (int p = 0; p < BSW; ++p) {
            int chunk = (wid * BSW + p) * 64 + lane;
            int row = chunk >> 3, c8 = (chunk & 7) * 8;
            gload16(Bbase + (size_t)row * K + k0 + c8, &Bs[(wid * BSW + p) * 512]);
        }
        __syncthreads();
#pragma unroll
        for (int kc = 0; kc < 2; ++kc) {
            int ko = kc * 32 + g * 8;
            bf16x8 af[MI], bfr[4];
#pragma unroll
            for (int i = 0; i < MI; ++i)
                af[i] = *reinterpret_cast<const bf16x8*>(&As[(wr + i * 16 + l15) * 64 + ko]);
#pragma unroll
            for (int j = 0; j < 4; ++j)
                bfr[j] = *reinterpret_cast<const bf16x8*>(&Bs[(wc + j * 16 + l15) * 64 + ko]);
#pragma unroll
            for (int i = 0; i < MI; ++i)
#pragma unroll
                for (int j = 0; j < 4; ++j)
                    acc[i][j] = __builtin_amdgcn_mfma_f32_16x16x32_bf16(af[i], bfr[j], acc[i][j], 0, 0, 0);
        }
    }
    int mb = tm + wr + g * 4;
    int nb = tn + wc + l15;
#pragma unroll
    for (int i = 0; i < MI; ++i) {
#pragma unroll
        for (int j = 0; j < 4; ++j) {
            int n = nb + j * 16;
#pragma unroll
            for (int r = 0; r < 4; ++r) {
                int m = mb + i * 16 + r;
                float val = acc[i][j][r];
                if constexpr (EPI == 0) {
                    ((u16*)Cout)[(size_t)m * N + n] = f2bf(val);
                } else if constexpr (EPI == 1) {
                    ((float*)Cout)[(size_t)m * N + n] =
                        val + bias[n] + resid[(size_t)m * N + n];
                } else if constexpr (EPI == 2) {
                    float xg = val + bias[n];
                    float x3 = xg + 0.044715f * xg * xg * xg;
                    float tz = 0.7978845608028654f * x3;
                    float th = 1.0f - 2.0f / (1.0f + __expf(2.0f * tz));
                    ((u16*)Cout)[(size_t)m * N + n] = f2bf(0.5f * xg * (1.0f + th));
                } else {  // EPI 4: fused QKV epilogue
                    if (n < 1024) {
                        ((u16*)Cout)[(size_t)m * 1024 + n] = f2bf(val);
                    } else if (n < 2048) {
                        ((u16*)Cout2)[(size_t)m * 1024 + (n - 1024)] = f2bf(val);
                    } else {
                        int bb = m >> 11, ss = m & 2047;
                        ((u16*)Cout3)[((size_t)(bb * EMB + (n - 2048))) * SEQ + ss] = f2bf(val);
                    }
                }
            }
        }
    }
}

// ---------------- Flash attention (causal), bf16 MFMA ----------------
// One wave per block, 32 q-rows, KVBLK=64. Q pre-scaled by 1/8.
// Issue-early V loads + K tile prefetch (register double-buffer).
// Defer-max online softmax (THR=8); mask only on the final (diagonal) k-tile.
// Qb, Kb: [4096][1024] bf16; Vt: [2][1024][2048] bf16; ctx: [4096][1024] bf16
__global__ __launch_bounds__(64) void attn_kernel(
    const u16* __restrict__ Qb, const u16* __restrict__ Kb,
    const u16* __restrict__ Vt, u16* __restrict__ ctx) {
    __shared__ u16 P_lds[32][72];
    int bh = blockIdx.x;
    int b = bh >> 4, h = bh & 15;
    int qc = 63 - (int)blockIdx.y;  // heavy chunks dispatch first
    int lane = threadIdx.x;
    int l15 = lane & 15, g = lane >> 4;
    int qbase = qc * 32;

    const u16* Qrow = Qb + (size_t)(b * SEQ) * EMB + h * 64;
    const u16* Krow = Kb + (size_t)(b * SEQ) * EMB + h * 64;
    const u16* Vrow = Vt + (size_t)(b * EMB + h * 64) * SEQ;

    // Q fragments, pre-scaled by 0.125 (exact power of two -> no bf16 error)
    bf16x8 qf[2][2];
#pragma unroll
    for (int qt = 0; qt < 2; ++qt)
#pragma unroll
        for (int kc = 0; kc < 2; ++kc) {
            bf16x8 v = *reinterpret_cast<const bf16x8*>(
                Qrow + (size_t)(qbase + qt * 16 + l15) * EMB + kc * 32 + g * 8);
            bf16x8 sv;
#pragma unroll
            for (int e = 0; e < 8; ++e) sv[e] = (__bf16)((float)v[e] * 0.125f);
            qf[qt][kc] = sv;
        }

    f32x4 ctx_acc[2][4] = {};
    float mrun[2] = {-1e30f, -1e30f};
    float lrun[2] = {0.f, 0.f};
    int nkt = qc / 2 + 1;

    // preload K tile 0 (idx = kc*4 + ktile)
    bf16x8 kcur[8], knxt[8];
#pragma unroll
    for (int i = 0; i < 8; ++i) {
        int kc = i >> 2, ktile = i & 3;
        kcur[i] = *reinterpret_cast<const bf16x8*>(
            Krow + (size_t)(ktile * 16 + l15) * EMB + kc * 32 + g * 8);
    }

    for (int kt = 0; kt < nkt; ++kt) {
        int k0 = kt * 64;
        bool last = (kt == nkt - 1);
        // issue V loads for THIS tile now; consumed after softmax (latency hidden)
        bf16x8 vf[8];  // idx = kc*4 + dt
#pragma unroll
        for (int i = 0; i < 8; ++i) {
            int kc = i >> 2, dt = i & 3;
            vf[i] = *reinterpret_cast<const bf16x8*>(
                Vrow + (size_t)(dt * 16 + l15) * SEQ + k0 + kc * 32 + g * 8);
        }
        // S^T = K . Q^T  (sacc[ktile][qt]: row=key=g*4+r, col=q=l15)
        f32x4 sacc[4][2] = {};
#pragma unroll
        for (int kc = 0; kc < 2; ++kc)
#pragma unroll
            for (int ktile = 0; ktile < 4; ++ktile)
#pragma unroll
                for (int qt = 0; qt < 2; ++qt)
                    sacc[ktile][qt] = __builtin_amdgcn_mfma_f32_16x16x32_bf16(
                        kcur[kc * 4 + ktile], qf[qt][kc], sacc[ktile][qt], 0, 0, 0);
        // prefetch NEXT K tile; consumed next iteration (latency hidden under softmax+PV)
        if (kt + 1 < nkt) {
#pragma unroll
            for (int i = 0; i < 8; ++i) {
                int kc = i >> 2, ktile = i & 3;
                knxt[i] = *reinterpret_cast<const bf16x8*>(
                    Krow + (size_t)(k0 + 64 + ktile * 16 + l15) * EMB + kc * 32 + g * 8);
            }
        }
#pragma unroll
        for (int qt = 0; qt < 2; ++qt) {
            float sv[16];
            float tmax = -1e30f;
            if (last) {
                int q = qbase + qt * 16 + l15;
#pragma unroll
                for (int ktile = 0; ktile < 4; ++ktile)
#pragma unroll
                    for (int r = 0; r < 4; ++r) {
                        int key = k0 + ktile * 16 + g * 4 + r;
                        float sx = (key > q) ? -1e30f : sacc[ktile][qt][r];
                        sv[ktile * 4 + r] = sx;
                        tmax = fmaxf(tmax, sx);
                    }
            } else {
#pragma unroll
                for (int ktile = 0; ktile < 4; ++ktile)
#pragma unroll
                    for (int r = 0; r < 4; ++r) {
                        float sx = sacc[ktile][qt][r];
                        sv[ktile * 4 + r] = sx;
                        tmax = fmaxf(tmax, sx);
                    }
            }
            tmax = fmaxf(tmax, __shfl_xor(tmax, 16));
            tmax = fmaxf(tmax, __shfl_xor(tmax, 32));
            // defer-max: only rescale when the running max grew by >8
            if (!__all(tmax <= mrun[qt] + 8.0f)) {
                float mnew = fmaxf(mrun[qt], tmax);
                float corr = __expf(mrun[qt] - mnew);
                mrun[qt] = mnew;
                lrun[qt] *= corr;
                float corr4[4];
#pragma unroll
                for (int r = 0; r < 4; ++r) corr4[r] = __shfl(corr, g * 4 + r);
#pragma unroll
                for (int dt = 0; dt < 4; ++dt)
#pragma unroll
                    for (int r = 0; r < 4; ++r) ctx_acc[qt][dt][r] *= corr4[r];
            }
            float m = mrun[qt];
            float psum = 0.f;
#pragma unroll
            for (int idx = 0; idx < 16; ++idx) {
                float p = __expf(sv[idx] - m);
                sv[idx] = p;
                psum += p;
            }
            lrun[qt] += psum;
            // pack P -> bf16 (truncation) with one v_perm per pair
#pragma unroll
            for (int ktile = 0; ktile < 4; ++ktile) {
                uint2 w;
                w.x = pack_bf_trunc(sv[ktile * 4 + 1], sv[ktile * 4 + 0]);
                w.y = pack_bf_trunc(sv[ktile * 4 + 3], sv[ktile * 4 + 2]);
                *reinterpret_cast<uint2*>(&P_lds[qt * 16 + l15][ktile * 16 + g * 4]) = w;
            }
        }
        asm volatile("s_waitcnt lgkmcnt(0)" ::: "memory");
        // ctx += P . V
#pragma unroll
        for (int kc = 0; kc < 2; ++kc) {
            bf16x8 pf[2];
#pragma unroll
            for (int qt = 0; qt < 2; ++qt)
                pf[qt] = *reinterpret_cast<const bf16x8*>(&P_lds[qt * 16 + l15][kc * 32 + g * 8]);
#pragma unroll
            for (int dt = 0; dt < 4; ++dt)
#pragma unroll
                for (int qt = 0; qt < 2; ++qt)
                    ctx_acc[qt][dt] = __builtin_amdgcn_mfma_f32_16x16x32_bf16(
                        pf[qt], vf[kc * 4 + dt], ctx_acc[qt][dt], 0, 0, 0);
        }
#pragma unroll
        for (int i = 0; i < 8; ++i) kcur[i] = knxt[i];
    }
#pragma unroll
    for (int qt = 0; qt < 2; ++qt) {
        float lsum = lrun[qt];
        lsum += __shfl_xor(lsum, 16);
        lsum += __shfl_xor(lsum, 32);
        float d4[4];
#pragma unroll
        for (int r = 0; r < 4; ++r) d4[r] = __shfl(lsum, g * 4 + r);
#pragma unroll
        for (int dt = 0; dt < 4; ++dt)
#pragma unroll
            for (int r = 0; r < 4; ++r) {
                int q = qbase + qt * 16 + g * 4 + r;
                int d = h * 64 + dt * 16 + l15;
                ctx[(size_t)(b * SEQ + q) * EMB + d] = f2bf(ctx_acc[qt][dt][r] / d4[r]);
            }
    }
}

extern "C" void kernel_launch(void* const* d_in, const int* in_sizes, int n_in,
                              void* d_out, int out_size, void* d_ws, size_t ws_size,
                              hipStream_t stream) {
    const float* x    = (const float*)d_in[0];
    const float* Wq   = (const float*)d_in[1];
    const float* Wk   = (const float*)d_in[2];
    const float* Wv   = (const float*)d_in[3];
    const float* Wo   = (const float*)d_in[4];
    const float* bo   = (const float*)d_in[5];
    const float* ln1g = (const float*)d_in[6];
    const float* ln1b = (const float*)d_in[7];
    const float* ln2g = (const float*)d_in[8];
    const float* ln2b = (const float*)d_in[9];
    const float* W1   = (const float*)d_in[10];
    const float* b1   = (const float*)d_in[11];
    const float* W2   = (const float*)d_in[12];
    const float* b2   = (const float*)d_in[13];

    char* ws = (char*)d_ws;
    size_t off = 0;
    auto alloc = [&](size_t bytes) {
        void* p = ws + off;
        off += (bytes + 255) & ~(size_t)255;
        return p;
    };
    u16* h1     = (u16*)alloc((size_t)ROWS * EMB * 2);
    u16* Wqkvt  = (u16*)alloc((size_t)3 * EMB * EMB * 2);  // [3072][1024]
    u16* Wot    = (u16*)alloc((size_t)EMB * EMB * 2);
    u16* W1t    = (u16*)alloc((size_t)FF * EMB * 2);   // [4096][1024]
    u16* W2t    = (u16*)alloc((size_t)EMB * FF * 2);   // [1024][4096]
    u16* Qb     = (u16*)alloc((size_t)ROWS * EMB * 2);
    u16* Kb     = (u16*)alloc((size_t)ROWS * EMB * 2);
    u16* Vtb    = (u16*)alloc((size_t)BATCH * EMB * SEQ * 2);
    u16* ctxb   = (u16*)alloc((size_t)ROWS * EMB * 2);
    float* x2   = (float*)alloc((size_t)ROWS * EMB * 4);
    u16* h2     = (u16*)alloc((size_t)ROWS * EMB * 2);
    u16* ff1    = (u16*)alloc((size_t)ROWS * FF * 2);

    u16* Wqt = Wqkvt;                          // rows 0..1023
    u16* Wkt = Wqkvt + (size_t)EMB * EMB;      // rows 1024..2047
    u16* Wvt = Wqkvt + (size_t)2 * EMB * EMB;  // rows 2048..3071

    // fused square-weight transposes + the two FF transposes
    transpose4_f32_to_bf16<<<dim3(32, 32, 4), 256, 0, stream>>>(
        Wq, Wk, Wv, Wo, Wqt, Wkt, Wvt, Wot);
    transpose_f32_to_bf16<<<dim3(128, 32), 256, 0, stream>>>(W1, W1t, EMB, FF);
    transpose_f32_to_bf16<<<dim3(32, 128), 256, 0, stream>>>(W2, W2t, FF, EMB);

    ln_kernel<<<ROWS, 256, 0, stream>>>(x, ln1g, ln1b, h1);

    // fused QKV: C[4096][3072] split into Qb, Kb, Vt   (768 blocks = 3/CU)
    gemm_bf16<4, 128><<<dim3(32, 24), 256, 0, stream>>>(h1, Wqkvt, Qb, nullptr, nullptr,
                                                        Kb, Vtb, ROWS, 3072, EMB);

    attn_kernel<<<dim3(32, 64), 64, 0, stream>>>(Qb, Kb, Vtb, ctxb);

    // Wo: N=1024 -> BN=64 tile, 512 blocks = 2/CU
    gemm_bf16<1, 64><<<dim3(32, 16), 256, 0, stream>>>(ctxb, Wot, x2, bo, x,
                                                       nullptr, nullptr, ROWS, EMB, EMB);

    ln_kernel<<<ROWS, 256, 0, stream>>>(x2, ln2g, ln2b, h2);

    // W1: 1024 blocks = 4/CU
    gemm_bf16<2, 128><<<dim3(32, 32), 256, 0, stream>>>(h2, W1t, ff1, b1, nullptr,
                                                        nullptr, nullptr, ROWS, FF, EMB);
    // W2: N=1024 -> BN=64 tile, 512 blocks = 2/CU
    gemm_bf16<1, 64><<<dim3(32, 16), 256, 0, stream>>>(ff1, W2t, (float*)d_out, b2, x2,
                                                       nullptr, nullptr, ROWS, EMB, FF);
}

// Round 7
// 412.937 us; speedup vs baseline: 1.1648x; 1.0055x over previous
//
#include <hip/hip_runtime.h>

typedef __bf16 bf16x8 __attribute__((ext_vector_type(8)));
typedef float f32x4 __attribute__((ext_vector_type(4)));
typedef float f32x16 __attribute__((ext_vector_type(16)));
typedef unsigned int u32x4 __attribute__((ext_vector_type(4)));
typedef unsigned short u16;

#define EMB 1024
#define SEQ 2048
#define BATCH 2
#define HEADS 16
#define HEAD_DIM 64
#define FF 4096
#define ROWS (BATCH * SEQ)  // 4096

// 0.125 * log2(e): folded into Q at the QKV epilogue so softmax is pure exp2
#define QSCALE 0.18033688011112042f

static __device__ __forceinline__ u16 f2bf(float f) {
    unsigned int u = __builtin_bit_cast(unsigned int, f);
    unsigned int r = (u + 0x7FFFu + ((u >> 16) & 1u)) >> 16;
    return (u16)r;
}

// pack two f32 -> two bf16 (truncation) in ONE v_perm_b32: {lo16 = hi16(b), hi16 = hi16(a)}
static __device__ __forceinline__ unsigned int pack_bf_trunc(float a, float b) {
    return __builtin_amdgcn_perm(__builtin_bit_cast(unsigned int, a),
                                 __builtin_bit_cast(unsigned int, b), 0x07060302u);
}

// async global->LDS, 16B per lane. LDS dest must be wave-uniform base (HW adds lane*16).
static __device__ __forceinline__ void gload16(const u16* g, u16* l) {
    __builtin_amdgcn_global_load_lds(
        (const __attribute__((address_space(1))) unsigned int*)(const void*)g,
        (__attribute__((address_space(3))) unsigned int*)(void*)l, 16, 0, 0);
}

// ---------------- transpose + convert: f32 [R][C] -> bf16 [C][R] ----------------
__global__ __launch_bounds__(256) void transpose_f32_to_bf16(
    const float* __restrict__ in, u16* __restrict__ out, int R, int C) {
    __shared__ float tile[32][33];
    int c0 = blockIdx.x * 32, r0 = blockIdx.y * 32;
    int tx = threadIdx.x & 31, ty = threadIdx.x >> 5;  // ty: 0..7
#pragma unroll
    for (int i = 0; i < 32; i += 8)
        tile[ty + i][tx] = in[(size_t)(r0 + ty + i) * C + c0 + tx];
    __syncthreads();
#pragma unroll
    for (int i = 0; i < 32; i += 8)
        out[(size_t)(c0 + ty + i) * R + r0 + tx] = f2bf(tile[tx][ty + i]);
}

// fused 4x square (1024x1024) weight transpose, z selects the weight
__global__ __launch_bounds__(256) void transpose4_f32_to_bf16(
    const float* __restrict__ s0, const float* __restrict__ s1,
    const float* __restrict__ s2, const float* __restrict__ s3,
    u16* __restrict__ d0, u16* __restrict__ d1,
    u16* __restrict__ d2, u16* __restrict__ d3) {
    __shared__ float tile[32][33];
    const float* in;
    u16* out;
    switch (blockIdx.z) {
        case 0: in = s0; out = d0; break;
        case 1: in = s1; out = d1; break;
        case 2: in = s2; out = d2; break;
        default: in = s3; out = d3; break;
    }
    int c0 = blockIdx.x * 32, r0 = blockIdx.y * 32;
    int tx = threadIdx.x & 31, ty = threadIdx.x >> 5;
#pragma unroll
    for (int i = 0; i < 32; i += 8)
        tile[ty + i][tx] = in[(size_t)(r0 + ty + i) * EMB + c0 + tx];
    __syncthreads();
#pragma unroll
    for (int i = 0; i < 32; i += 8)
        out[(size_t)(c0 + ty + i) * EMB + r0 + tx] = f2bf(tile[tx][ty + i]);
}

// ---------------- LayerNorm: f32 [rows][1024] -> bf16 ----------------
__global__ __launch_bounds__(256) void ln_kernel(
    const float* __restrict__ x, const float* __restrict__ gamma,
    const float* __restrict__ beta, u16* __restrict__ out) {
    int row = blockIdx.x;
    int t = threadIdx.x;
    float4 v = reinterpret_cast<const float4*>(x + (size_t)row * EMB)[t];
    float s = v.x + v.y + v.z + v.w;
    float s2 = v.x * v.x + v.y * v.y + v.z * v.z + v.w * v.w;
#pragma unroll
    for (int off = 1; off < 64; off <<= 1) {
        s += __shfl_xor(s, off);
        s2 += __shfl_xor(s2, off);
    }
    __shared__ float sm[8];
    int wid = t >> 6;
    if ((t & 63) == 0) { sm[wid] = s; sm[wid + 4] = s2; }
    __syncthreads();
    s = sm[0] + sm[1] + sm[2] + sm[3];
    s2 = sm[4] + sm[5] + sm[6] + sm[7];
    float mean = s * (1.0f / EMB);
    float var = s2 * (1.0f / EMB) - mean * mean;
    float inv = rsqrtf(var + 1e-5f);
    float4 gv = reinterpret_cast<const float4*>(gamma)[t];
    float4 bv = reinterpret_cast<const float4*>(beta)[t];
    ushort4 o;
    o.x = f2bf((v.x - mean) * inv * gv.x + bv.x);
    o.y = f2bf((v.y - mean) * inv * gv.y + bv.y);
    o.z = f2bf((v.z - mean) * inv * gv.z + bv.z);
    o.w = f2bf((v.w - mean) * inv * gv.w + bv.w);
    reinterpret_cast<ushort4*>(out + (size_t)row * EMB)[t] = o;
}

// ---------------- GEMM: C[M][N] = A[M][K] (bf16) x Bt[N][K] (bf16) ----------------
// m97 structure: global_load_lds width-16 staging into linear [128|BN][64] LDS.
// Tile = 128 x BN. BN=128: 4 waves of 64x64 (acc 4x4). BN=64: 4 waves of 32x64 (acc 2x4).
// EPI 0: bf16 out.  EPI 1: f32 out = acc + bias[n] + resid.  EPI 2: bf16 gelu(acc+bias).
// EPI 4: fused QKV: n<1024 -> Q (scaled by QSCALE), n<2048 -> K, else V transposed.
template <int EPI, int BN>
__global__ __launch_bounds__(256) void gemm_bf16(
    const u16* __restrict__ A, const u16* __restrict__ B, void* __restrict__ Cout,
    const float* __restrict__ bias, const float* __restrict__ resid,
    void* __restrict__ Cout2, void* __restrict__ Cout3,
    int M, int N, int K) {
    __shared__ u16 As[128 * 64];
    __shared__ u16 Bs[BN * 64];
    constexpr int MI = (BN == 128) ? 4 : 2;  // 16-row frags per wave (rows)
    constexpr int BSW = BN / 32;             // B staging sweeps (A is always 4)
    int tm = blockIdx.x * 128;
    int tn = blockIdx.y * BN;
    int t = threadIdx.x;
    int lane = t & 63, wid = t >> 6;
    int wr, wc;
    if constexpr (BN == 128) { wr = (wid >> 1) * 64; wc = (wid & 1) * 64; }
    else { wr = wid * 32; wc = 0; }
    int l15 = lane & 15, g = lane >> 4;
    const u16* Abase = A + (size_t)tm * K;
    const u16* Bbase = B + (size_t)tn * K;
    f32x4 acc[MI][4] = {};
    for (int k0 = 0; k0 < K; k0 += 64) {
        __syncthreads();
#pragma unroll
        for (int p = 0; p < 4; ++p) {
            int chunk = (wid * 4 + p) * 64 + lane;   // 16B chunk id, 0..1023
            int row = chunk >> 3, c8 = (chunk & 7) * 8;
            gload16(Abase + (size_t)row * K + k0 + c8, &As[(wid * 4 + p) * 512]);
        }
#pragma unroll
        for (int p = 0; p < BSW; ++p) {
            int chunk = (wid * BSW + p) * 64 + lane;
            int row = chunk >> 3, c8 = (chunk & 7) * 8;
            gload16(Bbase + (size_t)row * K + k0 + c8, &Bs[(wid * BSW + p) * 512]);
        }
        __syncthreads();
#pragma unroll
        for (int kc = 0; kc < 2; ++kc) {
            int ko = kc * 32 + g * 8;
            bf16x8 af[MI], bfr[4];
#pragma unroll
            for (int i = 0; i < MI; ++i)
                af[i] = *reinterpret_cast<const bf16x8*>(&As[(wr + i * 16 + l15) * 64 + ko]);
#pragma unroll
            for (int j = 0; j < 4; ++j)
                bfr[j] = *reinterpret_cast<const bf16x8*>(&Bs[(wc + j * 16 + l15) * 64 + ko]);
#pragma unroll
            for (int i = 0; i < MI; ++i)
#pragma unroll
                for (int j = 0; j < 4; ++j)
                    acc[i][j] = __builtin_amdgcn_mfma_f32_16x16x32_bf16(af[i], bfr[j], acc[i][j], 0, 0, 0);
        }
    }
    int mb = tm + wr + g * 4;
    int nb = tn + wc + l15;
#pragma unroll
    for (int i = 0; i < MI; ++i) {
#pragma unroll
        for (int j = 0; j < 4; ++j) {
            int n = nb + j * 16;
#pragma unroll
            for (int r = 0; r < 4; ++r) {
                int m = mb + i * 16 + r;
                float val = acc[i][j][r];
                if constexpr (EPI == 0) {
                    ((u16*)Cout)[(size_t)m * N + n] = f2bf(val);
                } else if constexpr (EPI == 1) {
                    ((float*)Cout)[(size_t)m * N + n] =
                        val + bias[n] + resid[(size_t)m * N + n];
                } else if constexpr (EPI == 2) {
                    float xg = val + bias[n];
                    float x3 = xg + 0.044715f * xg * xg * xg;
                    float tz = 0.7978845608028654f * x3;
                    float th = 1.0f - 2.0f / (1.0f + __expf(2.0f * tz));
                    ((u16*)Cout)[(size_t)m * N + n] = f2bf(0.5f * xg * (1.0f + th));
                } else {  // EPI 4: fused QKV epilogue
                    if (n < 1024) {
                        ((u16*)Cout)[(size_t)m * 1024 + n] = f2bf(val * QSCALE);
                    } else if (n < 2048) {
                        ((u16*)Cout2)[(size_t)m * 1024 + (n - 1024)] = f2bf(val);
                    } else {
                        int bb = m >> 11, ss = m & 2047;
                        ((u16*)Cout3)[((size_t)(bb * EMB + (n - 2048))) * SEQ + ss] = f2bf(val);
                    }
                }
            }
        }
    }
}

// ---------------- Flash attention (causal), 32x32 MFMA, in-register P ----------------
// One wave per block, 32 q-rows, KVBLK=64. Q pre-scaled by 0.125*log2e (exp2 softmax).
// S^T = K.Q^T via mfma_32x32x16: lane owns q = lane&31; with partner lane^32 the pair
// holds all 64 keys. Softmax fully in-lane; P->bf16 A-frags via v_perm + permlane32_swap.
// No LDS, no barriers. ctx C/D: row q_reg=(r&3)+8*(r>>2)+4*hi, col d=lane&31.
// Qb, Kb: [4096][1024] bf16; Vt: [2][1024][2048] bf16; ctx: [4096][1024] bf16
__global__ __launch_bounds__(64, 2) void attn_kernel(
    const u16* __restrict__ Qb, const u16* __restrict__ Kb,
    const u16* __restrict__ Vt, u16* __restrict__ ctx) {
    int bh = blockIdx.x;
    int b = bh >> 4, h = bh & 15;
    int qc = 63 - (int)blockIdx.y;  // heavy chunks dispatch first
    int lane = threadIdx.x;
    int l31 = lane & 31, hi = lane >> 5;
    int hi8 = hi * 8, hi4 = hi * 4;
    int qbase = qc * 32;

    const u16* Qrow = Qb + (size_t)(b * SEQ) * EMB + h * 64;
    const u16* Krow = Kb + (size_t)(b * SEQ) * EMB + h * 64;
    const u16* Vrow = Vt + (size_t)(b * EMB + h * 64) * SEQ;

    // Q B-fragments: B[k=d=kc*16+hi8+e][col=q=l31]   (already scaled by QSCALE)
    bf16x8 qf[4];
#pragma unroll
    for (int kc = 0; kc < 4; ++kc)
        qf[kc] = *reinterpret_cast<const bf16x8*>(
            Qrow + (size_t)(qbase + l31) * EMB + kc * 16 + hi8);

    f32x16 ctx_acc[2] = {};
    float mrun = -1e30f;
    float lrun = 0.f;
    int nkt = qc / 2 + 1;

    // K A-fragments: A[key=kb*32+l31][d=kc*16+hi8+e], idx = kb*4+kc. Preload tile 0.
    bf16x8 kcur[8];
#pragma unroll
    for (int i = 0; i < 8; ++i) {
        int kb = i >> 2, kc = i & 3;
        kcur[i] = *reinterpret_cast<const bf16x8*>(
            Krow + (size_t)(kb * 32 + l31) * EMB + kc * 16 + hi8);
    }

    for (int kt = 0; kt < nkt; ++kt) {
        int k0 = kt * 64;
        bool last = (kt == nkt - 1);
        // V B-frags for THIS tile, issued early: B[k=hi8+e][col=d=dt*32+l31], idx=ks*2+dt
        bf16x8 vf[8];
#pragma unroll
        for (int i = 0; i < 8; ++i) {
            int ks = i >> 1, dt = i & 1;
            vf[i] = *reinterpret_cast<const bf16x8*>(
                Vrow + (size_t)(dt * 32 + l31) * SEQ + k0 + ks * 16 + hi8);
        }
        // S^T = K . Q^T : sacc[kb][r] = S^T[key = k0+kb*32+(r&3)+8*(r>>2)+hi4][q = l31]
        f32x16 sacc[2] = {};
#pragma unroll
        for (int kb = 0; kb < 2; ++kb)
#pragma unroll
            for (int kc = 0; kc < 4; ++kc)
                sacc[kb] = __builtin_amdgcn_mfma_f32_32x32x16_bf16(
                    kcur[kb * 4 + kc], qf[kc], sacc[kb], 0, 0, 0);
        // prefetch NEXT K tile into the same regs (consumed next iteration)
        if (kt + 1 < nkt) {
#pragma unroll
            for (int i = 0; i < 8; ++i) {
                int kb = i >> 2, kc = i & 3;
                kcur[i] = *reinterpret_cast<const bf16x8*>(
                    Krow + (size_t)(k0 + 64 + kb * 32 + l31) * EMB + kc * 16 + hi8);
            }
        }
        // ---- softmax (all per-lane; this lane owns 32 of the 64 keys of q=l31) ----
        float sv[32];
        float tmax = -1e30f;
        if (last) {
            int q = qbase + l31;
#pragma unroll
            for (int kb = 0; kb < 2; ++kb)
#pragma unroll
                for (int r = 0; r < 16; ++r) {
                    int key = k0 + kb * 32 + (r & 3) + 8 * (r >> 2) + hi4;
                    float sx = (key > q) ? -1e30f : sacc[kb][r];
                    sv[kb * 16 + r] = sx;
                    tmax = fmaxf(tmax, sx);
                }
        } else {
#pragma unroll
            for (int kb = 0; kb < 2; ++kb)
#pragma unroll
                for (int r = 0; r < 16; ++r) {
                    float sx = sacc[kb][r];
                    sv[kb * 16 + r] = sx;
                    tmax = fmaxf(tmax, sx);
                }
        }
        tmax = fmaxf(tmax, __shfl_xor(tmax, 32));  // partner holds the other 32 keys
        // defer-max: rescale only when running max grew by >8 (base-2 domain)
        if (!__all(tmax <= mrun + 8.0f)) {
            float mnew = fmaxf(mrun, tmax);
            float corr = __builtin_amdgcn_exp2f(mrun - mnew);
            mrun = mnew;
            lrun *= corr;
            float corr_r[16];
#pragma unroll
            for (int r = 0; r < 16; ++r)
                corr_r[r] = __shfl(corr, (r & 3) + 8 * (r >> 2) + hi4);
#pragma unroll
            for (int dt = 0; dt < 2; ++dt)
#pragma unroll
                for (int r = 0; r < 16; ++r) ctx_acc[dt][r] *= corr_r[r];
        }
        float m = mrun;
        float psum = 0.f;
#pragma unroll
        for (int i = 0; i < 32; ++i) {
            float p = __builtin_amdgcn_exp2f(sv[i] - m);
            sv[i] = p;
            psum += p;
        }
        lrun += psum;
        // ---- P -> bf16 A-frags in-register: pa[ks] covers keys ks*16..ks*16+15 ----
        bf16x8 pa[4];
#pragma unroll
        for (int ks = 0; ks < 4; ++ks) {
            int bse = (ks >> 1) * 16 + (ks & 1) * 8;
            unsigned int w0 = pack_bf_trunc(sv[bse + 1], sv[bse + 0]);
            unsigned int wA = pack_bf_trunc(sv[bse + 5], sv[bse + 4]);
            unsigned int w1 = pack_bf_trunc(sv[bse + 3], sv[bse + 2]);
            unsigned int wB = pack_bf_trunc(sv[bse + 7], sv[bse + 6]);
            asm("v_permlane32_swap_b32 %0, %1" : "+v"(w0), "+v"(wA));
            asm("v_permlane32_swap_b32 %0, %1" : "+v"(w1), "+v"(wB));
            u32x4 words = {w0, w1, wA, wB};
            pa[ks] = __builtin_bit_cast(bf16x8, words);
        }
        // ---- ctx += P . V ----
#pragma unroll
        for (int ks = 0; ks < 4; ++ks)
#pragma unroll
            for (int dt = 0; dt < 2; ++dt)
                ctx_acc[dt] = __builtin_amdgcn_mfma_f32_32x32x16_bf16(
                    pa[ks], vf[ks * 2 + dt], ctx_acc[dt], 0, 0, 0);
    }
    // ---- epilogue: normalize and write ----
    lrun += __shfl_xor(lrun, 32);
    float linv = 1.0f / lrun;
    float li[16];
#pragma unroll
    for (int r = 0; r < 16; ++r)
        li[r] = __shfl(linv, (r & 3) + 8 * (r >> 2) + hi4);
#pragma unroll
    for (int dt = 0; dt < 2; ++dt)
#pragma unroll
        for (int r = 0; r < 16; ++r) {
            int q = qbase + (r & 3) + 8 * (r >> 2) + hi4;
            int d = h * 64 + dt * 32 + l31;
            ctx[(size_t)(b * SEQ + q) * EMB + d] = f2bf(ctx_acc[dt][r] * li[r]);
        }
}

extern "C" void kernel_launch(void* const* d_in, const int* in_sizes, int n_in,
                              void* d_out, int out_size, void* d_ws, size_t ws_size,
                              hipStream_t stream) {
    const float* x    = (const float*)d_in[0];
    const float* Wq   = (const float*)d_in[1];
    const float* Wk   = (const float*)d_in[2];
    const float* Wv   = (const float*)d_in[3];
    const float* Wo   = (const float*)d_in[4];
    const float* bo   = (const float*)d_in[5];
    const float* ln1g = (const float*)d_in[6];
    const float* ln1b = (const float*)d_in[7];
    const float* ln2g = (const float*)d_in[8];
    const float* ln2b = (const float*)d_in[9];
    const float* W1   = (const float*)d_in[10];
    const float* b1   = (const float*)d_in[11];
    const float* W2   = (const float*)d_in[12];
    const float* b2   = (const float*)d_in[13];

    char* ws = (char*)d_ws;
    size_t off = 0;
    auto alloc = [&](size_t bytes) {
        void* p = ws + off;
        off += (bytes + 255) & ~(size_t)255;
        return p;
    };
    u16* h1     = (u16*)alloc((size_t)ROWS * EMB * 2);
    u16* Wqkvt  = (u16*)alloc((size_t)3 * EMB * EMB * 2);  // [3072][1024]
    u16* Wot    = (u16*)alloc((size_t)EMB * EMB * 2);
    u16* W1t    = (u16*)alloc((size_t)FF * EMB * 2);   // [4096][1024]
    u16* W2t    = (u16*)alloc((size_t)EMB * FF * 2);   // [1024][4096]
    u16* Qb     = (u16*)alloc((size_t)ROWS * EMB * 2);
    u16* Kb     = (u16*)alloc((size_t)ROWS * EMB * 2);
    u16* Vtb    = (u16*)alloc((size_t)BATCH * EMB * SEQ * 2);
    u16* ctxb   = (u16*)alloc((size_t)ROWS * EMB * 2);
    float* x2   = (float*)alloc((size_t)ROWS * EMB * 4);
    u16* h2     = (u16*)alloc((size_t)ROWS * EMB * 2);
    u16* ff1    = (u16*)alloc((size_t)ROWS * FF * 2);

    u16* Wqt = Wqkvt;                          // rows 0..1023
    u16* Wkt = Wqkvt + (size_t)EMB * EMB;      // rows 1024..2047
    u16* Wvt = Wqkvt + (size_t)2 * EMB * EMB;  // rows 2048..3071

    // fused square-weight transposes + the two FF transposes
    transpose4_f32_to_bf16<<<dim3(32, 32, 4), 256, 0, stream>>>(
        Wq, Wk, Wv, Wo, Wqt, Wkt, Wvt, Wot);
    transpose_f32_to_bf16<<<dim3(128, 32), 256, 0, stream>>>(W1, W1t, EMB, FF);
    transpose_f32_to_bf16<<<dim3(32, 128), 256, 0, stream>>>(W2, W2t, FF, EMB);

    ln_kernel<<<ROWS, 256, 0, stream>>>(x, ln1g, ln1b, h1);

    // fused QKV: C[4096][3072] split into Qb (pre-scaled), Kb, Vt  (768 blocks = 3/CU)
    gemm_bf16<4, 128><<<dim3(32, 24), 256, 0, stream>>>(h1, Wqkvt, Qb, nullptr, nullptr,
                                                        Kb, Vtb, ROWS, 3072, EMB);

    attn_kernel<<<dim3(32, 64), 64, 0, stream>>>(Qb, Kb, Vtb, ctxb);

    // Wo: N=1024 -> BN=64 tile, 512 blocks = 2/CU
    gemm_bf16<1, 64><<<dim3(32, 16), 256, 0, stream>>>(ctxb, Wot, x2, bo, x,
                                                       nullptr, nullptr, ROWS, EMB, EMB);

    ln_kernel<<<ROWS, 256, 0, stream>>>(x2, ln2g, ln2b, h2);

    // W1: 1024 blocks = 4/CU
    gemm_bf16<2, 128><<<dim3(32, 32), 256, 0, stream>>>(h2, W1t, ff1, b1, nullptr,
                                                        nullptr, nullptr, ROWS, FF, EMB);
    // W2: N=1024 -> BN=64 tile, 512 blocks = 2/CU
    gemm_bf16<1, 64><<<dim3(32, 16), 256, 0, stream>>>(ff1, W2t, (float*)d_out, b2, x2,
                                                       nullptr, nullptr, ROWS, EMB, FF);
}